// Round 3
// baseline (410.756 us; speedup 1.0000x reference)
//
#include <hip/hip_runtime.h>

#define BSZ 8
#define SEQ 16
#define DIMN 512
#define SP 4096
#define KVL 4112

#define SCALE 0.0625f   // (512/2)^-0.5

// workspace layout (float offsets)
#define QBUF  0                      // 65536
#define KNEW  65536                  // 65536
#define VNEW  131072                 // 65536
#define PROBS 196608                 // 8*16*4112 = 526336
#define APART 722944                 // 33 * 65536 = 2162688
#define ATTEN 2885632                // 65536

// ---------------------------------------------------------------------------
// Kernel A: full-K projection.  grid (8b*4et, nm), block 256.
// Block: 16 rows x 128 e-cols, K=512.  Thread: 2 rows x 4 e-cols.
// X tile staged in LDS (coalesced); W walked sequentially per thread
// (L2-resident, 8x reuse across b-blocks).
// ---------------------------------------------------------------------------
__global__ __launch_bounds__(256) void proj_full(
    const float* __restrict__ X, const float* __restrict__ W0,
    const float* __restrict__ W1, const float* __restrict__ W2,
    float* __restrict__ O0, float* __restrict__ O1, float* __restrict__ O2)
{
  __shared__ float xs[SEQ][DIMN];   // 32 KB
  int b = blockIdx.x >> 2, et = blockIdx.x & 3;
  int m = blockIdx.y;
  const float* W = (m == 0) ? W0 : (m == 1) ? W1 : W2;
  float* O = (m == 0) ? O0 : (m == 1) ? O1 : O2;
  int t = threadIdx.x;

  const float4* xsrc = (const float4*)(X + (size_t)b * SEQ * DIMN);
  float4* xdst = (float4*)&xs[0][0];
#pragma unroll
  for (int i = 0; i < 8; ++i) xdst[t + i * 256] = xsrc[t + i * 256];
  __syncthreads();

  int e = et * 128 + (t & 31) * 4;
  int r0 = (t >> 5) * 2;
  float acc[2][4];
#pragma unroll
  for (int r = 0; r < 2; ++r)
#pragma unroll
    for (int i = 0; i < 4; ++i) acc[r][i] = 0.f;

  for (int d4 = 0; d4 < 128; ++d4) {
    float4 w[4];
#pragma unroll
    for (int i = 0; i < 4; ++i)
      w[i] = *(const float4*)(W + (size_t)(e + i) * DIMN + d4 * 4);
#pragma unroll
    for (int r = 0; r < 2; ++r) {
      float4 xv = *(const float4*)&xs[r0 + r][d4 * 4];
#pragma unroll
      for (int i = 0; i < 4; ++i)
        acc[r][i] += xv.x * w[i].x + xv.y * w[i].y + xv.z * w[i].z + xv.w * w[i].w;
    }
  }
#pragma unroll
  for (int r = 0; r < 2; ++r) {
    float4 o = make_float4(acc[r][0], acc[r][1], acc[r][2], acc[r][3]);
    *(float4*)(O + (size_t)(b * SEQ + r0 + r) * DIMN + e) = o;
  }
}

// ---------------------------------------------------------------------------
// Kernel C: scores (round-1 layout, measured faster).  One wave per position;
// lane holds q[.., lane*8..lane*8+7] for ALL 16 queries (128 VGPRs);
// each K row read exactly once per block.  grid (8, 65 chunks of 64 pos).
// ---------------------------------------------------------------------------
__global__ __launch_bounds__(256) void scores_kernel(
    const float* __restrict__ qbuf, const float* __restrict__ cache_k,
    const float* __restrict__ knew, float* __restrict__ weight)
{
  int b = blockIdx.x;
  int p0 = blockIdx.y * 64;
  int len = KVL - p0; if (len > 64) len = 64;
  int t = threadIdx.x, lane = t & 63, w = t >> 6;

  float4 qa[SEQ], qb[SEQ];
  const float* qbase = qbuf + (size_t)b * SEQ * DIMN + lane * 8;
#pragma unroll
  for (int s = 0; s < SEQ; ++s) {
    qa[s] = *(const float4*)(qbase + s * DIMN);
    qb[s] = *(const float4*)(qbase + s * DIMN + 4);
  }

  bool b1 = (lane & 1), b2 = (lane & 2), b4 = (lane & 4), b8 = (lane & 8);
  int niter = (len - w + 3) >> 2;   // positions p0 + w + 4*i
#pragma unroll 2
  for (int i = 0; i < niter; ++i) {
    int p = p0 + w + 4 * i;
    const float* krow = (p < SP)
        ? (cache_k + ((size_t)b * 8192 + p) * DIMN)
        : (knew + (size_t)(b * SEQ + (p - SP)) * DIMN);
    float4 ka = *(const float4*)(krow + lane * 8);
    float4 kb = *(const float4*)(krow + lane * 8 + 4);

    float acc[SEQ];
#pragma unroll
    for (int s = 0; s < SEQ; ++s) {
      acc[s] = qa[s].x * ka.x + qa[s].y * ka.y + qa[s].z * ka.z + qa[s].w * ka.w
             + qb[s].x * kb.x + qb[s].y * kb.y + qb[s].z * kb.z + qb[s].w * kb.w;
    }
    float r8[8];
#pragma unroll
    for (int u = 0; u < 8; ++u) {
      float keep = b1 ? acc[u + 8] : acc[u];
      float send = b1 ? acc[u] : acc[u + 8];
      r8[u] = keep + __shfl_xor(send, 1);
    }
    float r4[4];
#pragma unroll
    for (int u = 0; u < 4; ++u) {
      float keep = b2 ? r8[u + 4] : r8[u];
      float send = b2 ? r8[u] : r8[u + 4];
      r4[u] = keep + __shfl_xor(send, 2);
    }
    float r2[2];
#pragma unroll
    for (int u = 0; u < 2; ++u) {
      float keep = b4 ? r4[u + 2] : r4[u];
      float send = b4 ? r4[u] : r4[u + 2];
      r2[u] = keep + __shfl_xor(send, 4);
    }
    float keep = b8 ? r2[1] : r2[0];
    float send = b8 ? r2[0] : r2[1];
    float r1 = keep + __shfl_xor(send, 8);
    r1 += __shfl_xor(r1, 16);
    r1 += __shfl_xor(r1, 32);

    if (lane < 16) {
      int s = ((lane & 1) << 3) | ((lane & 2) << 1) | ((lane & 4) >> 1) | ((lane & 8) >> 3);
      weight[(size_t)(b * SEQ + s) * KVL + p] = r1 * SCALE;
    }
  }
}

// ---------------------------------------------------------------------------
// Kernel D: softmax over KVL per (b,s) row.  probs = softmax(weight + mask)
// ---------------------------------------------------------------------------
__global__ __launch_bounds__(256) void softmax_kernel(
    const float* __restrict__ weight, const float* __restrict__ mask,
    float* __restrict__ probs)
{
  int row = blockIdx.x;          // b*16 + s
  int s = row & 15;
  int t = threadIdx.x, lane = t & 63, w = t >> 6;
  const float* src = weight + (size_t)row * KVL;
  const float* msk = mask + (size_t)s * KVL;

  float vals[17];
  float mx = -1e30f;
#pragma unroll
  for (int i = 0; i < 17; ++i) {
    int p = t + i * 256;
    if (p < KVL) { vals[i] = src[p] + msk[p]; mx = fmaxf(mx, vals[i]); }
    else vals[i] = -1e30f;
  }
  for (int off = 32; off >= 1; off >>= 1) mx = fmaxf(mx, __shfl_xor(mx, off));
  __shared__ float redm[4], reds[4];
  if (lane == 0) redm[w] = mx;
  __syncthreads();
  mx = fmaxf(fmaxf(redm[0], redm[1]), fmaxf(redm[2], redm[3]));

  float sum = 0.f;
#pragma unroll
  for (int i = 0; i < 17; ++i) {
    int p = t + i * 256;
    if (p < KVL) { vals[i] = __expf(vals[i] - mx); sum += vals[i]; }
  }
  for (int off = 32; off >= 1; off >>= 1) sum += __shfl_xor(sum, off);
  if (lane == 0) reds[w] = sum;
  __syncthreads();
  sum = reds[0] + reds[1] + reds[2] + reds[3];
  float inv = 1.0f / sum;

  float* dst = probs + (size_t)row * KVL;
#pragma unroll
  for (int i = 0; i < 17; ++i) {
    int p = t + i * 256;
    if (p < KVL) dst[p] = vals[i] * inv;
  }
}

// ---------------------------------------------------------------------------
// Kernel E: atten partials.  grid (8, 33 chunks of 128 pos), block 256.
// Thread owns v-cols {t, t+256} for all 16 queries; probs chunk in LDS.
// ---------------------------------------------------------------------------
__global__ __launch_bounds__(256) void attnv_kernel(
    const float* __restrict__ probs, const float* __restrict__ cache_v,
    const float* __restrict__ vnew, float* __restrict__ apart)
{
  __shared__ float pl[SEQ][128];   // 8 KB
  int b = blockIdx.x, c = blockIdx.y;
  int p0 = c * 128;
  int len = KVL - p0; if (len > 128) len = 128;
  int t = threadIdx.x;

  for (int i = t; i < SEQ * 128; i += 256) {
    int q = i >> 7, j = i & 127;
    pl[q][j] = (j < len) ? probs[(size_t)(b * SEQ + q) * KVL + p0 + j] : 0.f;
  }
  __syncthreads();

  float acc0[SEQ], acc1[SEQ];
#pragma unroll
  for (int q = 0; q < SEQ; ++q) { acc0[q] = 0.f; acc1[q] = 0.f; }

  int nj4 = len >> 2;   // 32 (last chunk: 4)
  for (int j4 = 0; j4 < nj4; ++j4) {
    float4 pv[SEQ];
#pragma unroll
    for (int q = 0; q < SEQ; ++q) pv[q] = *(const float4*)&pl[q][j4 * 4];
#pragma unroll
    for (int jj = 0; jj < 4; ++jj) {
      int p = p0 + j4 * 4 + jj;
      const float* vrow = (p < SP)
          ? (cache_v + ((size_t)b * 8192 + p) * DIMN)
          : (vnew + (size_t)(b * SEQ + (p - SP)) * DIMN);
      float va = vrow[t], vb = vrow[t + 256];
#pragma unroll
      for (int q = 0; q < SEQ; ++q) {
        float pj = (jj == 0) ? pv[q].x : (jj == 1) ? pv[q].y : (jj == 2) ? pv[q].z : pv[q].w;
        acc0[q] += pj * va;
        acc1[q] += pj * vb;
      }
    }
  }
  float* outp = apart + (size_t)c * 65536 + (size_t)b * SEQ * DIMN;
#pragma unroll
  for (int q = 0; q < SEQ; ++q) {
    outp[q * DIMN + t] = acc0[q];
    outp[q * DIMN + t + 256] = acc1[q];
  }
}

// ---------------------------------------------------------------------------
// Kernel F: reduce 33 position-chunk partials -> atten
// ---------------------------------------------------------------------------
__global__ __launch_bounds__(256) void reduce_att(
    const float* __restrict__ apart, float* __restrict__ atten)
{
  int idx = blockIdx.x * 256 + threadIdx.x;   // grid 256 -> 65536
  float s = 0.f;
  for (int c = 0; c < 33; ++c) s += apart[(size_t)c * 65536 + idx];
  atten[idx] = s;
}

// ---------------------------------------------------------------------------
extern "C" void kernel_launch(void* const* d_in, const int* in_sizes, int n_in,
                              void* d_out, int out_size, void* d_ws, size_t ws_size,
                              hipStream_t stream) {
  const float* x       = (const float*)d_in[0];
  // d_in[1] = start_pos (fixed 4096, baked into constants)
  const float* mask    = (const float*)d_in[2];
  const float* Wq      = (const float*)d_in[3];
  const float* Wk      = (const float*)d_in[4];
  const float* Wv      = (const float*)d_in[5];
  const float* Wo      = (const float*)d_in[6];
  const float* cache_k = (const float*)d_in[7];
  const float* cache_v = (const float*)d_in[8];
  float* out    = (float*)d_out;           // [8,16,512]
  float* weight = out + 65536;             // [8,16,4112]
  float* ws     = (float*)d_ws;

  proj_full<<<dim3(32, 3), 256, 0, stream>>>(
      x, Wq, Wk, Wv, ws + QBUF, ws + KNEW, ws + VNEW);
  scores_kernel<<<dim3(8, 65), 256, 0, stream>>>(ws + QBUF, cache_k, ws + KNEW, weight);
  softmax_kernel<<<dim3(128), 256, 0, stream>>>(weight, mask, ws + PROBS);
  attnv_kernel<<<dim3(8, 33), 256, 0, stream>>>(ws + PROBS, cache_v, ws + VNEW, ws + APART);
  reduce_att<<<dim3(256), 256, 0, stream>>>(ws + APART, ws + ATTEN);
  proj_full<<<dim3(32, 1), 256, 0, stream>>>(
      ws + ATTEN, Wo, Wo, Wo, out, out, out);
}

// Round 4
// 332.056 us; speedup vs baseline: 1.2370x; 1.2370x over previous
//
#include <hip/hip_runtime.h>

#define BSZ 8
#define SEQ 16
#define DIMN 512
#define SP 4096
#define KVL 4112

#define SCALE 0.0625f   // (512/2)^-0.5

// workspace layout (float offsets)
#define QBUF  0                      // 65536
#define KNEW  65536                  // 65536
#define VNEW  131072                 // 65536
#define STATS 196608                 // 256 (mx, inv per row)
#define APART 262144                 // 33 * 65536 = 2162688
#define ATTEN 2424832                // 65536

// ---------------------------------------------------------------------------
// Kernel A: projection, wave-per-W-row (coalesced 2KB row loads, same
// structure as scores).  grid (8 b, 8 row-chunks of 64, nm), block 256.
// Lane holds X[b][s][lane*8 .. +7] for all 16 s (128 VGPRs).
// out[b][s][e] = dot(X[b][s], W[e])  via ownership-halving tree reduction.
// ---------------------------------------------------------------------------
__global__ __launch_bounds__(256) void proj_rows(
    const float* __restrict__ X, const float* __restrict__ W0,
    const float* __restrict__ W1, const float* __restrict__ W2,
    float* __restrict__ O0, float* __restrict__ O1, float* __restrict__ O2)
{
  int b = blockIdx.x;
  int e0 = blockIdx.y * 64;
  int m = blockIdx.z;
  const float* W = (m == 0) ? W0 : (m == 1) ? W1 : W2;
  float* O = (m == 0) ? O0 : (m == 1) ? O1 : O2;
  int t = threadIdx.x, lane = t & 63, w = t >> 6;

  float4 xa[SEQ], xb[SEQ];
  const float* xbase = X + (size_t)b * SEQ * DIMN + lane * 8;
#pragma unroll
  for (int s = 0; s < SEQ; ++s) {
    xa[s] = *(const float4*)(xbase + s * DIMN);
    xb[s] = *(const float4*)(xbase + s * DIMN + 4);
  }

  bool b1 = (lane & 1), b2 = (lane & 2), b4 = (lane & 4), b8 = (lane & 8);
#pragma unroll 2
  for (int i = 0; i < 16; ++i) {
    int e = e0 + w + 4 * i;
    const float* wrow = W + (size_t)e * DIMN;
    float4 ka = *(const float4*)(wrow + lane * 8);
    float4 kb = *(const float4*)(wrow + lane * 8 + 4);

    float acc[SEQ];
#pragma unroll
    for (int s = 0; s < SEQ; ++s) {
      acc[s] = xa[s].x * ka.x + xa[s].y * ka.y + xa[s].z * ka.z + xa[s].w * ka.w
             + xb[s].x * kb.x + xb[s].y * kb.y + xb[s].z * kb.z + xb[s].w * kb.w;
    }
    float r8[8];
#pragma unroll
    for (int u = 0; u < 8; ++u) {
      float keep = b1 ? acc[u + 8] : acc[u];
      float send = b1 ? acc[u] : acc[u + 8];
      r8[u] = keep + __shfl_xor(send, 1);
    }
    float r4[4];
#pragma unroll
    for (int u = 0; u < 4; ++u) {
      float keep = b2 ? r8[u + 4] : r8[u];
      float send = b2 ? r8[u] : r8[u + 4];
      r4[u] = keep + __shfl_xor(send, 2);
    }
    float r2[2];
#pragma unroll
    for (int u = 0; u < 2; ++u) {
      float keep = b4 ? r4[u + 2] : r4[u];
      float send = b4 ? r4[u] : r4[u + 2];
      r2[u] = keep + __shfl_xor(send, 4);
    }
    float keep = b8 ? r2[1] : r2[0];
    float send = b8 ? r2[0] : r2[1];
    float r1 = keep + __shfl_xor(send, 8);
    r1 += __shfl_xor(r1, 16);
    r1 += __shfl_xor(r1, 32);

    if (lane < 16) {
      int s = ((lane & 1) << 3) | ((lane & 2) << 1) | ((lane & 4) >> 1) | ((lane & 8) >> 3);
      O[(size_t)(b * SEQ + s) * DIMN + e] = r1;
    }
  }
}

// ---------------------------------------------------------------------------
// Kernel C: scores (round-1 layout).  One wave per position; lane holds
// q[.., lane*8..+7] for ALL 16 queries; each K row read once per block.
// grid (8, 65 chunks of 64 pos), block 256.
// ---------------------------------------------------------------------------
__global__ __launch_bounds__(256) void scores_kernel(
    const float* __restrict__ qbuf, const float* __restrict__ cache_k,
    const float* __restrict__ knew, float* __restrict__ weight)
{
  int b = blockIdx.x;
  int p0 = blockIdx.y * 64;
  int len = KVL - p0; if (len > 64) len = 64;
  int t = threadIdx.x, lane = t & 63, w = t >> 6;

  float4 qa[SEQ], qb[SEQ];
  const float* qbase = qbuf + (size_t)b * SEQ * DIMN + lane * 8;
#pragma unroll
  for (int s = 0; s < SEQ; ++s) {
    qa[s] = *(const float4*)(qbase + s * DIMN);
    qb[s] = *(const float4*)(qbase + s * DIMN + 4);
  }

  bool b1 = (lane & 1), b2 = (lane & 2), b4 = (lane & 4), b8 = (lane & 8);
  int niter = (len - w + 3) >> 2;   // positions p0 + w + 4*i
#pragma unroll 2
  for (int i = 0; i < niter; ++i) {
    int p = p0 + w + 4 * i;
    const float* krow = (p < SP)
        ? (cache_k + ((size_t)b * 8192 + p) * DIMN)
        : (knew + (size_t)(b * SEQ + (p - SP)) * DIMN);
    float4 ka = *(const float4*)(krow + lane * 8);
    float4 kb = *(const float4*)(krow + lane * 8 + 4);

    float acc[SEQ];
#pragma unroll
    for (int s = 0; s < SEQ; ++s) {
      acc[s] = qa[s].x * ka.x + qa[s].y * ka.y + qa[s].z * ka.z + qa[s].w * ka.w
             + qb[s].x * kb.x + qb[s].y * kb.y + qb[s].z * kb.z + qb[s].w * kb.w;
    }
    float r8[8];
#pragma unroll
    for (int u = 0; u < 8; ++u) {
      float keep = b1 ? acc[u + 8] : acc[u];
      float send = b1 ? acc[u] : acc[u + 8];
      r8[u] = keep + __shfl_xor(send, 1);
    }
    float r4[4];
#pragma unroll
    for (int u = 0; u < 4; ++u) {
      float keep = b2 ? r8[u + 4] : r8[u];
      float send = b2 ? r8[u] : r8[u + 4];
      r4[u] = keep + __shfl_xor(send, 2);
    }
    float r2[2];
#pragma unroll
    for (int u = 0; u < 2; ++u) {
      float keep = b4 ? r4[u + 2] : r4[u];
      float send = b4 ? r4[u] : r4[u + 2];
      r2[u] = keep + __shfl_xor(send, 4);
    }
    float keep = b8 ? r2[1] : r2[0];
    float send = b8 ? r2[0] : r2[1];
    float r1 = keep + __shfl_xor(send, 8);
    r1 += __shfl_xor(r1, 16);
    r1 += __shfl_xor(r1, 32);

    if (lane < 16) {
      int s = ((lane & 1) << 3) | ((lane & 2) << 1) | ((lane & 4) >> 1) | ((lane & 8) >> 3);
      weight[(size_t)(b * SEQ + s) * KVL + p] = r1 * SCALE;
    }
  }
}

// ---------------------------------------------------------------------------
// Kernel D: softmax stats per (b,s) row: mx = max(w+m), inv = 1/sum(exp).
// stats[row*2] = mx, stats[row*2+1] = inv.  grid 128, block 256.
// ---------------------------------------------------------------------------
__global__ __launch_bounds__(256) void softmax_stats(
    const float* __restrict__ weight, const float* __restrict__ mask,
    float* __restrict__ stats)
{
  int row = blockIdx.x;          // b*16 + s
  int s = row & 15;
  int t = threadIdx.x, lane = t & 63, w = t >> 6;
  const float* src = weight + (size_t)row * KVL;
  const float* msk = mask + (size_t)s * KVL;

  float vals[17];
  float mx = -1e30f;
#pragma unroll
  for (int i = 0; i < 17; ++i) {
    int p = t + i * 256;
    if (p < KVL) { vals[i] = src[p] + msk[p]; mx = fmaxf(mx, vals[i]); }
    else vals[i] = -1e30f;
  }
  for (int off = 32; off >= 1; off >>= 1) mx = fmaxf(mx, __shfl_xor(mx, off));
  __shared__ float redm[4], reds[4];
  if (lane == 0) redm[w] = mx;
  __syncthreads();
  mx = fmaxf(fmaxf(redm[0], redm[1]), fmaxf(redm[2], redm[3]));

  float sum = 0.f;
#pragma unroll
  for (int i = 0; i < 17; ++i) {
    int p = t + i * 256;
    if (p < KVL) sum += __expf(vals[i] - mx);
  }
  for (int off = 32; off >= 1; off >>= 1) sum += __shfl_xor(sum, off);
  if (lane == 0) reds[w] = sum;
  __syncthreads();
  if (t == 0) {
    sum = reds[0] + reds[1] + reds[2] + reds[3];
    stats[row * 2] = mx;
    stats[row * 2 + 1] = 1.0f / sum;
  }
}

// ---------------------------------------------------------------------------
// Kernel E: atten partials, probs computed on the fly from weight+mask+stats.
// grid (8, 33 chunks of 128 pos), block 256.  Thread owns v-cols {t, t+256}.
// ---------------------------------------------------------------------------
__global__ __launch_bounds__(256) void attnv_kernel(
    const float* __restrict__ weight, const float* __restrict__ mask,
    const float* __restrict__ stats, const float* __restrict__ cache_v,
    const float* __restrict__ vnew, float* __restrict__ apart)
{
  __shared__ float pl[SEQ][128];   // 8 KB
  __shared__ float st[SEQ][2];
  int b = blockIdx.x, c = blockIdx.y;
  int p0 = c * 128;
  int len = KVL - p0; if (len > 128) len = 128;
  int t = threadIdx.x;

  if (t < SEQ * 2) ((float*)st)[t] = stats[b * SEQ * 2 + t];
  __syncthreads();

  for (int i = t; i < SEQ * 128; i += 256) {
    int q = i >> 7, j = i & 127;
    float v = 0.f;
    if (j < len) {
      int p = p0 + j;
      v = __expf(weight[(size_t)(b * SEQ + q) * KVL + p]
                 + mask[(size_t)q * KVL + p] - st[q][0]) * st[q][1];
    }
    pl[q][j] = v;
  }
  __syncthreads();

  float acc0[SEQ], acc1[SEQ];
#pragma unroll
  for (int q = 0; q < SEQ; ++q) { acc0[q] = 0.f; acc1[q] = 0.f; }

  int nj4 = len >> 2;   // 32 (last chunk: 4)
  for (int j4 = 0; j4 < nj4; ++j4) {
    float4 pv[SEQ];
#pragma unroll
    for (int q = 0; q < SEQ; ++q) pv[q] = *(const float4*)&pl[q][j4 * 4];
#pragma unroll
    for (int jj = 0; jj < 4; ++jj) {
      int p = p0 + j4 * 4 + jj;
      const float* vrow = (p < SP)
          ? (cache_v + ((size_t)b * 8192 + p) * DIMN)
          : (vnew + (size_t)(b * SEQ + (p - SP)) * DIMN);
      float va = vrow[t], vb = vrow[t + 256];
#pragma unroll
      for (int q = 0; q < SEQ; ++q) {
        float pj = (jj == 0) ? pv[q].x : (jj == 1) ? pv[q].y : (jj == 2) ? pv[q].z : pv[q].w;
        acc0[q] += pj * va;
        acc1[q] += pj * vb;
      }
    }
  }
  float* outp = apart + (size_t)c * 65536 + (size_t)b * SEQ * DIMN;
#pragma unroll
  for (int q = 0; q < SEQ; ++q) {
    outp[q * DIMN + t] = acc0[q];
    outp[q * DIMN + t + 256] = acc1[q];
  }
}

// ---------------------------------------------------------------------------
// Kernel F: reduce 33 position-chunk partials -> atten
// ---------------------------------------------------------------------------
__global__ __launch_bounds__(256) void reduce_att(
    const float* __restrict__ apart, float* __restrict__ atten)
{
  int idx = blockIdx.x * 256 + threadIdx.x;   // grid 256 -> 65536
  float s = 0.f;
  for (int c = 0; c < 33; ++c) s += apart[(size_t)c * 65536 + idx];
  atten[idx] = s;
}

// ---------------------------------------------------------------------------
extern "C" void kernel_launch(void* const* d_in, const int* in_sizes, int n_in,
                              void* d_out, int out_size, void* d_ws, size_t ws_size,
                              hipStream_t stream) {
  const float* x       = (const float*)d_in[0];
  // d_in[1] = start_pos (fixed 4096, baked into constants)
  const float* mask    = (const float*)d_in[2];
  const float* Wq      = (const float*)d_in[3];
  const float* Wk      = (const float*)d_in[4];
  const float* Wv      = (const float*)d_in[5];
  const float* Wo      = (const float*)d_in[6];
  const float* cache_k = (const float*)d_in[7];
  const float* cache_v = (const float*)d_in[8];
  float* out    = (float*)d_out;           // [8,16,512]
  float* weight = out + 65536;             // [8,16,4112]
  float* ws     = (float*)d_ws;

  // q/k/v projections: wave-per-row, coalesced W streams
  proj_rows<<<dim3(8, 8, 3), 256, 0, stream>>>(
      x, Wq, Wk, Wv, ws + QBUF, ws + KNEW, ws + VNEW);
  // scores -> weight output (pre-mask, scaled)
  scores_kernel<<<dim3(8, 65), 256, 0, stream>>>(ws + QBUF, cache_k, ws + KNEW, weight);
  // per-row softmax stats (mx, 1/sum)
  softmax_stats<<<dim3(128), 256, 0, stream>>>(weight, mask, ws + STATS);
  // probs-on-the-fly @ v_full (split over position chunks)
  attnv_kernel<<<dim3(8, 33), 256, 0, stream>>>(
      weight, mask, ws + STATS, cache_v, ws + VNEW, ws + APART);
  reduce_att<<<dim3(256), 256, 0, stream>>>(ws + APART, ws + ATTEN);
  // output projection
  proj_rows<<<dim3(8, 8, 1), 256, 0, stream>>>(
      ws + ATTEN, Wo, Wo, Wo, out, out, out);
}